// Round 1
// baseline (863.499 us; speedup 1.0000x reference)
//
#include <hip/hip_runtime.h>
#include <math.h>

// B=2, S=2048, E=2048, H=16, D=128; qkv width = E + 2D = 2304.
// d_in: 0=hidden(f32 B,S,E) 1=mask(bool, ignored: exact causal) 2=c_attn_w(f32 E,2304)
//       3=c_attn_b(f32 2304) 4=c_proj_w(f32 E,E) 5=c_proj_b(f32 E)
// d_out: f32 (B,S,E)

typedef __attribute__((ext_vector_type(8))) short short8;
typedef __attribute__((ext_vector_type(8))) __bf16 bf16x8;
typedef __attribute__((ext_vector_type(4))) float floatx4;

__device__ __forceinline__ unsigned short f2bf(float f) {
    unsigned u = __builtin_bit_cast(unsigned, f);
    u += 0x7fffu + ((u >> 16) & 1u);          // RNE
    return (unsigned short)(u >> 16);
}

// --- MFMA wrapper: tolerate either builtin signature (short8 or __bf16 x8) ---
template <typename V>
__device__ __forceinline__ auto mfma_try(V a, V b, floatx4 c, int)
    -> decltype(__builtin_amdgcn_mfma_f32_16x16x32_bf16(a, b, c, 0, 0, 0)) {
    return __builtin_amdgcn_mfma_f32_16x16x32_bf16(a, b, c, 0, 0, 0);
}
template <typename V>
__device__ __forceinline__ floatx4 mfma_try(V a, V b, floatx4 c, long) {
    return __builtin_amdgcn_mfma_f32_16x16x32_bf16(
        __builtin_bit_cast(bf16x8, a), __builtin_bit_cast(bf16x8, b), c, 0, 0, 0);
}
__device__ __forceinline__ floatx4 mfma_bf16(short8 a, short8 b, floatx4 c) {
    return mfma_try(a, b, c, 0);
}

// ---------------- GEMM with bias, bf16 MFMA, 128x128x64 tile, 4 waves ---------
// MODE 0: output bf16 (qkv); cols < 2048 (=Q) scaled by 1/sqrt(128). ABF16: A dtype.
// MODE 1: output fp32 (final projection).
template <int N, int MODE, int ABF16>
__global__ __launch_bounds__(256) void gemm_bias_kernel(
    const void* __restrict__ Av, const float* __restrict__ B,
    const float* __restrict__ bias, void* __restrict__ Cout, int K)
{
    constexpr int BK = 64;
    __shared__ unsigned short As[128][BK + 8];
    __shared__ unsigned short Bs[128][BK + 8];   // B stored transposed: Bs[n][k]

    const int tid  = threadIdx.x;
    const int lane = tid & 63;
    const int wid  = tid >> 6;
    const int wr = wid >> 1, wc = wid & 1;
    const int m0 = blockIdx.y * 128, n0 = blockIdx.x * 128;
    const int lg = lane >> 4, li = lane & 15;

    floatx4 acc[4][4] = {};

    for (int k0 = 0; k0 < K; k0 += BK) {
        __syncthreads();
        // ---- stage A tile (128 x 64) ----
        if constexpr (ABF16) {
            const unsigned short* A = (const unsigned short*)Av;
            #pragma unroll
            for (int i = 0; i < 4; ++i) {
                int idx = tid + i * 256;          // 1024 x ushort8
                int row = idx >> 3, c8 = idx & 7;
                *reinterpret_cast<short8*>(&As[row][c8 * 8]) =
                    *reinterpret_cast<const short8*>(&A[(size_t)(m0 + row) * K + k0 + c8 * 8]);
            }
        } else {
            const float* A = (const float*)Av;
            #pragma unroll
            for (int i = 0; i < 8; ++i) {
                int idx = tid + i * 256;          // 2048 x float4
                int row = idx >> 4, c4 = idx & 15;
                float4 v = *reinterpret_cast<const float4*>(&A[(size_t)(m0 + row) * K + k0 + c4 * 4]);
                unsigned short* dst = &As[row][c4 * 4];
                dst[0] = f2bf(v.x); dst[1] = f2bf(v.y); dst[2] = f2bf(v.z); dst[3] = f2bf(v.w);
            }
        }
        // ---- stage B tile (64 x 128) transposed into Bs[n][k] ----
        #pragma unroll
        for (int i = 0; i < 8; ++i) {
            int idx = tid + i * 256;              // 2048 x float4
            int row = idx >> 5, c4 = idx & 31;    // row = k (0..63), c4*4 = n offset
            float4 v = *reinterpret_cast<const float4*>(&B[(size_t)(k0 + row) * N + n0 + c4 * 4]);
            Bs[c4 * 4 + 0][row] = f2bf(v.x);
            Bs[c4 * 4 + 1][row] = f2bf(v.y);
            Bs[c4 * 4 + 2][row] = f2bf(v.z);
            Bs[c4 * 4 + 3][row] = f2bf(v.w);
        }
        __syncthreads();
        // ---- compute: 2 k-chunks of 32, 16 MFMA each ----
        #pragma unroll
        for (int kk = 0; kk < 2; ++kk) {
            short8 af[4], bfv[4];
            #pragma unroll
            for (int m = 0; m < 4; ++m)
                af[m] = *reinterpret_cast<const short8*>(&As[wr * 64 + m * 16 + li][kk * 32 + lg * 8]);
            #pragma unroll
            for (int n = 0; n < 4; ++n)
                bfv[n] = *reinterpret_cast<const short8*>(&Bs[wc * 64 + n * 16 + li][kk * 32 + lg * 8]);
            #pragma unroll
            for (int m = 0; m < 4; ++m)
                #pragma unroll
                for (int n = 0; n < 4; ++n)
                    acc[m][n] = mfma_bf16(af[m], bfv[n], acc[m][n]);
        }
    }

    // ---- epilogue: C[row=(lane>>4)*4+r][col=lane&15] (m89-verified) ----
    #pragma unroll
    for (int m = 0; m < 4; ++m) {
        #pragma unroll
        for (int n = 0; n < 4; ++n) {
            const int col = n0 + wc * 64 + n * 16 + li;
            const float bv = bias[col];
            #pragma unroll
            for (int r = 0; r < 4; ++r) {
                const int row = m0 + wr * 64 + m * 16 + lg * 4 + r;
                float v = acc[m][n][r] + bv;
                if constexpr (MODE == 0) {
                    if (col < 2048) v *= 0.08838834764831845f;   // 1/sqrt(128), applied to Q
                    ((unsigned short*)Cout)[(size_t)row * N + col] = f2bf(v);
                } else {
                    ((float*)Cout)[(size_t)row * N + col] = v;
                }
            }
        }
    }
}

// ---------------- MQA flash attention --------------------------------------
// Block: 256 thr = 4 waves; handles (b, h, 64 q-rows), wave w owns 16 q-rows.
// K/V tiles (32 keys x 128) staged in LDS, shared by all waves (MQA).
__global__ __launch_bounds__(256) void attn_kernel(
    const unsigned short* __restrict__ qkv,   // [B*S][2304] bf16 bits; Q pre-scaled
    unsigned short* __restrict__ attn_out)    // [B*S][2048] bf16
{
    constexpr int S = 2048, D = 128, QKV = 2304, E = 2048;
    __shared__ unsigned short Ks[32][136];        // keys x d (+8 pad)
    __shared__ unsigned short Vs[128][40];        // d x keys (transposed, +8 pad)
    __shared__ unsigned short Ps[4][16][40];      // per-wave P: qrow x key (+8 pad)

    const int tid  = threadIdx.x;
    const int lane = tid & 63;
    const int wid  = tid >> 6;
    const int qt = blockIdx.x, h = blockIdx.y, b = blockIdx.z;
    const int qbase = qt * 64;
    const int qw = qbase + wid * 16;
    const int lg = lane >> 4, li = lane & 15;
    const size_t baseBS = (size_t)b * S;

    // Q fragments: 16 rows x 128 d, A-operand layout (row=lane&15, k=(lane>>4)*8+j)
    short8 qf[4];
    #pragma unroll
    for (int f = 0; f < 4; ++f)
        qf[f] = *reinterpret_cast<const short8*>(
            &qkv[(baseBS + qw + li) * QKV + h * D + f * 32 + lg * 8]);

    floatx4 o[8] = {};
    float mrow[4] = {-1e30f, -1e30f, -1e30f, -1e30f};
    float lrow[4] = {0.f, 0.f, 0.f, 0.f};

    const int nkt = (qbase + 64) / 32;            // causal: tiles of 32 keys
    for (int kt = 0; kt < nkt; ++kt) {
        const int k0 = kt * 32;
        __syncthreads();
        // stage K tile (row-major) and V tile (transposed)
        #pragma unroll
        for (int i = 0; i < 2; ++i) {
            int idx = tid + i * 256;              // 512 x ushort8
            int key = idx >> 4, d8 = idx & 15;
            *reinterpret_cast<short8*>(&Ks[key][d8 * 8]) =
                *reinterpret_cast<const short8*>(&qkv[(baseBS + k0 + key) * QKV + E + d8 * 8]);
        }
        #pragma unroll
        for (int i = 0; i < 2; ++i) {
            int idx = tid + i * 256;
            int key = idx >> 4, d8 = idx & 15;
            short8 v = *reinterpret_cast<const short8*>(
                &qkv[(baseBS + k0 + key) * QKV + E + D + d8 * 8]);
            #pragma unroll
            for (int j = 0; j < 8; ++j)
                Vs[d8 * 8 + j][key] = (unsigned short)v[j];
        }
        __syncthreads();

        if (k0 <= qw + 15) {                      // wave-uniform activity test
            // scores: S0 = Q x K[0:16]^T, S1 = Q x K[16:32]^T
            floatx4 s0 = {0.f, 0.f, 0.f, 0.f}, s1 = {0.f, 0.f, 0.f, 0.f};
            #pragma unroll
            for (int f = 0; f < 4; ++f) {
                short8 kf0 = *reinterpret_cast<const short8*>(&Ks[li][f * 32 + lg * 8]);
                short8 kf1 = *reinterpret_cast<const short8*>(&Ks[16 + li][f * 32 + lg * 8]);
                s0 = mfma_bf16(qf[f], kf0, s0);
                s1 = mfma_bf16(qf[f], kf1, s1);
            }
            // online softmax per accumulator row r (global q = qw + lg*4 + r)
            #pragma unroll
            for (int r = 0; r < 4; ++r) {
                const int qg = qw + lg * 4 + r;
                float a = s0[r]; if (k0 + li > qg)      a = -1e30f;
                float c = s1[r]; if (k0 + 16 + li > qg) c = -1e30f;
                float rm = fmaxf(a, c);
                #pragma unroll
                for (int x = 1; x <= 8; x <<= 1) rm = fmaxf(rm, __shfl_xor(rm, x));
                const float mn = fmaxf(mrow[r], rm);
                const float scale = __expf(mrow[r] - mn);
                const float p0 = __expf(a - mn);
                const float p1 = __expf(c - mn);
                float rs = p0 + p1;
                #pragma unroll
                for (int x = 1; x <= 8; x <<= 1) rs += __shfl_xor(rs, x);
                lrow[r] = lrow[r] * scale + rs;
                mrow[r] = mn;
                #pragma unroll
                for (int db = 0; db < 8; ++db) o[db][r] *= scale;
                Ps[wid][lg * 4 + r][li]      = f2bf(p0);
                Ps[wid][lg * 4 + r][16 + li] = f2bf(p1);
            }
            // wave-internal LDS transpose of P -> A-fragment
            asm volatile("s_waitcnt lgkmcnt(0)" ::: "memory");
            short8 pa = *reinterpret_cast<const short8*>(&Ps[wid][li][lg * 8]);
            #pragma unroll
            for (int db = 0; db < 8; ++db) {
                short8 vf = *reinterpret_cast<const short8*>(&Vs[db * 16 + li][lg * 8]);
                o[db] = mfma_bf16(pa, vf, o[db]);
            }
        }
    }

    // normalize + write attn (bf16), layout [b*S + q][h*128 + d]
    #pragma unroll
    for (int db = 0; db < 8; ++db) {
        #pragma unroll
        for (int r = 0; r < 4; ++r) {
            const int q = qw + lg * 4 + r;
            const float v = o[db][r] / lrow[r];
            attn_out[(baseBS + q) * E + h * D + db * 16 + li] = f2bf(v);
        }
    }
}

extern "C" void kernel_launch(void* const* d_in, const int* in_sizes, int n_in,
                              void* d_out, int out_size, void* d_ws, size_t ws_size,
                              hipStream_t stream) {
    (void)in_sizes; (void)n_in; (void)out_size; (void)ws_size;
    const float* hidden   = (const float*)d_in[0];
    // d_in[1] = attention_mask: exactly causal tril -> handled analytically
    const float* c_attn_w = (const float*)d_in[2];
    const float* c_attn_b = (const float*)d_in[3];
    const float* c_proj_w = (const float*)d_in[4];
    const float* c_proj_b = (const float*)d_in[5];
    float* out = (float*)d_out;

    unsigned short* qkv  = (unsigned short*)d_ws;                              // 4096x2304 bf16
    unsigned short* attn = (unsigned short*)((char*)d_ws + (size_t)4096 * 2304 * 2); // 4096x2048 bf16

    // 1) qkv = hidden @ c_attn_w + b  (Q pre-scaled), bf16 out
    gemm_bias_kernel<2304, 0, 0><<<dim3(18, 32), 256, 0, stream>>>(
        hidden, c_attn_w, c_attn_b, qkv, 2048);
    // 2) MQA causal flash attention
    attn_kernel<<<dim3(32, 16, 2), 256, 0, stream>>>(qkv, attn);
    // 3) out = attn @ c_proj_w + b, fp32 out
    gemm_bias_kernel<2048, 1, 1><<<dim3(16, 32), 256, 0, stream>>>(
        attn, c_proj_w, c_proj_b, out, 2048);
}